// Round 4
// baseline (9154.601 us; speedup 1.0000x reference)
//
#include <hip/hip_runtime.h>

typedef __attribute__((ext_vector_type(8))) short short8;
typedef __attribute__((ext_vector_type(4))) float f32x4;

#define NN 4096     // neurons
#define NB 32       // batch
#define TSTEPS 291  // t = 0..290 (last record at t=290; steps 291..299 unused)
#define FF_T 300    // ff_input time stride
#define NBLK 256    // grid size == CU count; 1 block/CU capacity guaranteed

// float -> bf16 round-to-nearest-even, raw bits in a short
__device__ __forceinline__ short f2bf(float x) {
    unsigned u = __builtin_bit_cast(unsigned, x);
    unsigned r = (u + 0x7FFFu + ((u >> 16) & 1u)) >> 16;
    return (short)r;
}
__device__ __forceinline__ unsigned pack2bf(float x0, float x1) {
    return ((unsigned)(unsigned short)f2bf(x0))
         | (((unsigned)(unsigned short)f2bf(x1)) << 16);
}

// Coherent-point store/load for FLAGS only (global_store/load_dword sc1 —
// bypass L2, visible cross-XCD immediately).
__device__ __forceinline__ void st_coh(int* p, int v) {
    __hip_atomic_store(p, v, __ATOMIC_RELAXED, __HIP_MEMORY_SCOPE_AGENT);
}
__device__ __forceinline__ int ld_coh(const int* p) {
    return __hip_atomic_load(p, __ATOMIC_RELAXED, __HIP_MEMORY_SCOPE_AGENT);
}

// Two-hop grid barrier (R0-proven topology) with a RELEASE fence on the
// arrival edge. Change vs R0: rates are now published with NORMAL cached
// stores (they land in per-XCD L2, counted done at __syncthreads' vmcnt
// drain), and the release fence emits buffer_wbl2 + waitcnt — dirty L2
// (the block's 1KB of rates + any out lines) is written back to L3 BEFORE
// the arrival flag store issues. Flag-visible therefore implies
// data-in-L3. R0's sc1 data stores wrote through to HBM (WRITE_SIZE
// showed 74MB = 291x256KB) and forced every step's refill to ride an HBM
// round trip (FETCH showed ~1MB/step of rates re-reads); this keeps the
// recurrent state entirely in L3, refilled via per-XCD L2 amplification.
// Block 0 aggregates 256 arrival flags; others poll the single go word.
// One acquire fence (buffer_inv) per block per step on the exit edge.
__device__ __forceinline__ void grid_barrier(int* __restrict__ flags,
                                             int* __restrict__ go, int epoch) {
    __syncthreads();   // all waves: s_waitcnt vmcnt(0) — rates stores in L2
    __builtin_amdgcn_fence(__ATOMIC_RELEASE, "agent");  // wbl2: L2 -> L3
    if (threadIdx.x == 0)
        st_coh(&flags[blockIdx.x], epoch);
    if (blockIdx.x == 0) {
        // master: thread t waits for block t's arrival, then publish go
        while (ld_coh(&flags[threadIdx.x]) < epoch)
            __builtin_amdgcn_s_sleep(1);
        __syncthreads();
        if (threadIdx.x == 0)
            st_coh(go, epoch);
    }
    if (threadIdx.x == 0) {
        while (ld_coh(go) < epoch)
            __builtin_amdgcn_s_sleep(2);
    }
    __syncthreads();
    __builtin_amdgcn_fence(__ATOMIC_ACQUIRE, "agent");  // buffer_inv only
}

// Persistent kernel. One WG per CU; WG c owns output columns [16c,16c+16)
// for all 32 batches. W lives in registers as MFMA B-frags (128 VGPRs/wave)
// for the whole run. Per-neuron fp32 state (rec, rate, window-acc) in
// registers: thread owns elements (b = tid>>3, n = n0 + (tid&7)*2 + {0,1}).
__global__ __launch_bounds__(256, 1)
void rnn_kernel(const float* __restrict__ W,
                const float* __restrict__ ff,
                const float* __restrict__ rec0p,
                float* __restrict__ out,
                int* __restrict__ flags,
                int* __restrict__ go,
                short* __restrict__ ratesA,
                short* __restrict__ ratesB)
{
    const int tid  = threadIdx.x;
    const int wave = tid >> 6;
    const int lane = tid & 63;
    const int n0   = blockIdx.x * 16;

    __shared__ float part[4][32][18];   // per-wave K-partials (padded)

    // per-thread state element indices
    const int sb  = tid >> 3;           // batch 0..31
    const int nl0 = (tid & 7) * 2;      // even neuron-local index 0..14

    // ---- init: rec0, rates0 = relu(ff[:,0] + rec0)
    const size_t sidx = (size_t)sb * NN + n0 + nl0;
    float rc0 = rec0p[sidx], rc1 = rec0p[sidx + 1];
    const float* ff0p = ff + ((size_t)sb * FF_T) * NN + n0 + nl0;
    float rt0 = fmaxf(ff0p[0] + rc0, 0.0f);
    float rt1 = fmaxf(ff0p[1] + rc1, 0.0f);
    float ac0 = 0.0f, ac1 = 0.0f;
    *(int*)(ratesA + sidx) = (int)pack2bf(rt0, rt1);   // cached store

    // ---- W (fp32 [k][n]) -> register bf16 B-fragments.
    // wave w covers k in [w*1024, (w+1)*1024); for K-step kt, lane holds
    // B[k = w*1024 + kt*32 + (lane>>4)*8 + j][n = n0 + (lane&15)], j=0..7
    short8 Bfr[32];
    {
        const int ncol  = n0 + (lane & 15);
        const size_t kb = (size_t)(wave * 1024 + ((lane >> 4) * 8));
        #pragma unroll
        for (int kt = 0; kt < 32; ++kt) {
            short8 f;
            #pragma unroll
            for (int j = 0; j < 8; ++j) {
                f[j] = f2bf(W[(kb + (size_t)kt * 32 + j) * NN + ncol]);
            }
            Bfr[kt] = f;
        }
    }

    int epoch = 1;
    grid_barrier(flags, go, epoch);   // rates0 written back to L3, visible

    // A-frag: lane reads rates[m][k], m = lane&15 (+16 for 2nd M-tile),
    // k = wave*1024 + kt*32 + (lane>>4)*8 + j (contiguous -> short8 load).
    // Normal cached loads: after buffer_inv, the first block on an XCD
    // fills L2 from L3; the other 31 blocks hit L2 (broadcast
    // amplification). No HBM involvement for rates in steady state.
    const int arow     = lane & 15;
    const int acolbase = wave * 1024 + ((lane >> 4) * 8);

    for (int t = 0; t < TSTEPS; ++t) {
        const short* __restrict__ rbuf = (t & 1) ? ratesB : ratesA;
        short* __restrict__ wbuf       = (t & 1) ? ratesA : ratesB;

        // prefetch this step's ff early to overlap with the MFMA loop
        const float* ffp = ff + ((size_t)sb * FF_T + t) * NN + n0 + nl0;
        const float ffv0 = ffp[0];
        const float ffv1 = ffp[1];

        f32x4 acc0 = {0.f, 0.f, 0.f, 0.f};
        f32x4 acc1 = {0.f, 0.f, 0.f, 0.f};
        const short* pa0 = rbuf + (size_t)arow * NN + acolbase;
        const short* pa1 = pa0 + 16 * NN;
        #pragma unroll
        for (int kt = 0; kt < 32; ++kt) {
            short8 a0 = *(const short8*)(pa0 + kt * 32);
            short8 a1 = *(const short8*)(pa1 + kt * 32);
            acc0 = __builtin_amdgcn_mfma_f32_16x16x32_bf16(a0, Bfr[kt], acc0, 0, 0, 0);
            acc1 = __builtin_amdgcn_mfma_f32_16x16x32_bf16(a1, Bfr[kt], acc1, 0, 0, 0);
        }

        // C/D layout: col = lane&15, row = (lane>>4)*4 + reg  [m89-verified]
        const int prow = (lane >> 4) * 4;
        const int pcol = lane & 15;
        #pragma unroll
        for (int r = 0; r < 4; ++r) {
            part[wave][prow + r][pcol]      = acc0[r];
            part[wave][16 + prow + r][pcol] = acc1[r];
        }
        __syncthreads();

        // fused update on this thread's two elements (state in registers)
        const float h0 = part[0][sb][nl0] + part[1][sb][nl0]
                       + part[2][sb][nl0] + part[3][sb][nl0];
        const float h1 = part[0][sb][nl0+1] + part[1][sb][nl0+1]
                       + part[2][sb][nl0+1] + part[3][sb][nl0+1];
        rc0 = rc0 * 0.95122945f + h0 * 0.05f;   // exp(-dt/tau_syn), dt/tau_syn
        rc1 = rc1 * 0.95122945f + h1 * 0.05f;
        rt0 = rt0 * 0.90483743f + fmaxf(ffv0 + rc0, 0.0f) * 0.1f; // exp(-dt/tau), dt/tau
        rt1 = rt1 * 0.90483743f + fmaxf(ffv1 + rc1, 0.0f) * 0.1f;
        if (t >= 90) { ac0 += rt0; ac1 += rt1; }
        // publish new rates with a NORMAL cached store; the barrier's
        // release fence (wbl2) pushes it to L3 before the flag goes up.
        *(int*)(wbuf + sidx) = (int)pack2bf(rt0, rt1);

        // record: windows end at t = 100,110,...,290 (first window = 11 terms
        // /10, matching cs[100]-cs[89] in the reference)
        if (t >= 100 && (t % 10) == 0) {
            const int w = (t - 100) / 10;
            float* op = out + ((size_t)sb * 20 + w) * NN + n0 + nl0;
            op[0] = ac0 * 0.1f;
            op[1] = ac1 * 0.1f;
            ac0 = 0.0f; ac1 = 0.0f;
        }

        epoch++;
        grid_barrier(flags, go, epoch);  // publishes new rates; orders LDS reuse
    }
}

extern "C" void kernel_launch(void* const* d_in, const int* in_sizes, int n_in,
                              void* d_out, int out_size, void* d_ws, size_t ws_size,
                              hipStream_t stream)
{
    const float* W    = (const float*)d_in[0];   // Wab_T [4096,4096] fp32, row-major [k][n]
    const float* ff   = (const float*)d_in[1];   // [32,300,4096] fp32
    const float* rec0 = (const float*)d_in[2];   // [32,4096] fp32
    float* out = (float*)d_out;                  // [32,20,4096] fp32

    int*   flags  = (int*)d_ws;                   // 256 arrival flags
    int*   go     = (int*)d_ws + 512;             // single release word
    short* ratesA = (short*)((char*)d_ws + 4096); // bf16 rates double buffer
    short* ratesB = ratesA + NB * NN;

    hipMemsetAsync(d_ws, 0, 4096, stream);        // graph-capturable memset node

    rnn_kernel<<<dim3(NBLK), dim3(256), 0, stream>>>(W, ff, rec0, out,
                                                     flags, go, ratesA, ratesB);
}

// Round 5
// 4740.265 us; speedup vs baseline: 1.9312x; 1.9312x over previous
//
#include <hip/hip_runtime.h>

typedef __attribute__((ext_vector_type(8))) short short8;
typedef __attribute__((ext_vector_type(4))) float f32x4;

#define NN 4096     // neurons
#define NB 32       // batch
#define TSTEPS 291  // t = 0..290 (last record at t=290; steps 291..299 unused)
#define FF_T 300    // ff_input time stride
#define NBLK 256    // grid size == CU count; 1 block/CU capacity guaranteed
#define FSTR 64     // flag stride in ints (256B per flag -> own cache line)

// float -> bf16 round-to-nearest-even, raw bits in a short
__device__ __forceinline__ short f2bf(float x) {
    unsigned u = __builtin_bit_cast(unsigned, x);
    unsigned r = (u + 0x7FFFu + ((u >> 16) & 1u)) >> 16;
    return (short)r;
}
__device__ __forceinline__ unsigned pack2bf(float x0, float x1) {
    return ((unsigned)(unsigned short)f2bf(x0))
         | (((unsigned)(unsigned short)f2bf(x1)) << 16);
}

// Coherent-point store/load (global_store/load_dword sc1 — bypass L2,
// visible cross-XCD without any fence). R4 proved the alternative
// (cached stores + per-step agent release fence/buffer_wbl2) costs
// +14 us/step with IDENTICAL HBM traffic — sc1 stores are the right
// publish path on this chip.
__device__ __forceinline__ void st_coh(int* p, int v) {
    __hip_atomic_store(p, v, __ATOMIC_RELAXED, __HIP_MEMORY_SCOPE_AGENT);
}
__device__ __forceinline__ int ld_coh(const int* p) {
    return __hip_atomic_load(p, __ATOMIC_RELAXED, __HIP_MEMORY_SCOPE_AGENT);
}

// rates fragment layout (units: shorts): [k>>5][m>>4][(k>>3)&3][m&15][k&7]
// Exactly the 16x16x32 MFMA A-fragment lane order (correctness verified
// R1/R2: absmax identical). Consumer wave w reads its K-slab as contiguous
// 1KB chunks (lane addr = chunk_base + lane*16B) — uniform channel
// distribution — instead of R0's 16-lane x 8KB-stride scatter. Producer
// publishes exactly ONE packed dword per thread (its two neurons are
// adjacent k&7 slots).
__device__ __forceinline__ int foff(int m, int k) {
    return ((k >> 5) << 10) | ((m >> 4) << 9) | (((k >> 3) & 3) << 7)
         | ((m & 15) << 3) | (k & 7);
}

// One-hop all-to-all grid barrier with padded flags. Arrival = one plain
// sc1 store to the block's OWN 256B-padded flag line (parallel across
// blocks; no RMW — R1's atomicAdd serialized the critical word).
// Completion = thread i polls flag i directly; the serial chain is
// last-arrival-visible -> one poll period. vs R0's two-hop this removes
// the master-detect hop, the go-publication hop, and block 0's systematic
// extra latency. Padding is the fix for R2's poison (128 flags packed in
// 2 cache lines -> all poll traffic on 2 L3 lines); here 256 flags live
// on 256 distinct lines. __syncthreads before arrival drains each wave's
// vmcnt, so flag visibility implies rates visibility. One acquire fence
// (buffer_inv) per block per step keeps normal cached A-loads correct
// while preserving per-XCD L2 broadcast amplification.
__device__ __forceinline__ void grid_barrier(int* __restrict__ flags, int epoch) {
    __syncthreads();   // all waves: s_waitcnt vmcnt(0) — rates stores visible-ordered
    if (threadIdx.x == 0)
        st_coh(&flags[(size_t)blockIdx.x * FSTR], epoch);
    while (ld_coh(&flags[(size_t)threadIdx.x * FSTR]) < epoch)
        __builtin_amdgcn_s_sleep(2);
    __syncthreads();
    __builtin_amdgcn_fence(__ATOMIC_ACQUIRE, "agent");  // buffer_inv only
}

// Persistent kernel. One WG per CU; WG c owns output columns [16c,16c+16)
// for all 32 batches. W lives in registers as MFMA B-frags (128 VGPRs/wave)
// for the whole run. Per-neuron fp32 state (rec, rate, window-acc) in
// registers: thread owns elements (b = tid>>3, n = n0 + (tid&7)*2 + {0,1}).
__global__ __launch_bounds__(256, 1)
void rnn_kernel(const float* __restrict__ W,
                const float* __restrict__ ff,
                const float* __restrict__ rec0p,
                float* __restrict__ out,
                int* __restrict__ flags,
                short* __restrict__ ratesA,
                short* __restrict__ ratesB)
{
    const int tid  = threadIdx.x;
    const int wave = tid >> 6;
    const int lane = tid & 63;
    const int n0   = blockIdx.x * 16;

    __shared__ float part[4][32][18];   // per-wave K-partials (padded)

    // per-thread state element indices
    const int sb  = tid >> 3;           // batch 0..31
    const int nl0 = (tid & 7) * 2;      // even neuron-local index 0..14
    const int fo  = foff(sb, n0 + nl0); // fragment dword slot (even)

    // ---- init: rec0, rates0 = relu(ff[:,0] + rec0)
    const size_t sidx = (size_t)sb * NN + n0 + nl0;
    float rc0 = rec0p[sidx], rc1 = rec0p[sidx + 1];
    const float* ff0p = ff + ((size_t)sb * FF_T) * NN + n0 + nl0;
    float rt0 = fmaxf(ff0p[0] + rc0, 0.0f);
    float rt1 = fmaxf(ff0p[1] + rc1, 0.0f);
    float ac0 = 0.0f, ac1 = 0.0f;
    st_coh((int*)(ratesA + fo), (int)pack2bf(rt0, rt1));

    // ---- W (fp32 [k][n]) -> register bf16 B-fragments.
    // wave w covers k in [w*1024, (w+1)*1024); for K-step kt, lane holds
    // B[k = w*1024 + kt*32 + (lane>>4)*8 + j][n = n0 + (lane&15)], j=0..7
    short8 Bfr[32];
    {
        const int ncol  = n0 + (lane & 15);
        const size_t kb = (size_t)(wave * 1024 + ((lane >> 4) * 8));
        #pragma unroll
        for (int kt = 0; kt < 32; ++kt) {
            short8 f;
            #pragma unroll
            for (int j = 0; j < 8; ++j) {
                f[j] = f2bf(W[(kb + (size_t)kt * 32 + j) * NN + ncol]);
            }
            Bfr[kt] = f;
        }
    }

    int epoch = 1;
    grid_barrier(flags, epoch);   // rates0 globally visible

    // A-loads: contiguous fragment stream. Wave w owns shorts
    // [w*32768, (w+1)*32768); per kt two 1KB coalesced chunks
    // (m-tiles 0/1 at +0 / +512 shorts).
    const int wl = (wave << 15) + (lane << 3);

    for (int t = 0; t < TSTEPS; ++t) {
        const short* __restrict__ rbuf = (t & 1) ? ratesB : ratesA;
        short* __restrict__ wbuf       = (t & 1) ? ratesA : ratesB;

        // this step's ff: issued at top of step (R0 placement), consumed
        // after the MFMA loop — HBM latency overlaps the MFMA chain
        const float* ffp = ff + ((size_t)sb * FF_T + t) * NN + n0 + nl0;
        const float ffv0 = ffp[0];
        const float ffv1 = ffp[1];

        f32x4 acc0 = {0.f, 0.f, 0.f, 0.f};
        f32x4 acc1 = {0.f, 0.f, 0.f, 0.f};
        const short* pw = rbuf + wl;
        #pragma unroll
        for (int kt = 0; kt < 32; ++kt) {
            short8 a0 = *(const short8*)(pw + (kt << 10));
            short8 a1 = *(const short8*)(pw + (kt << 10) + 512);
            acc0 = __builtin_amdgcn_mfma_f32_16x16x32_bf16(a0, Bfr[kt], acc0, 0, 0, 0);
            acc1 = __builtin_amdgcn_mfma_f32_16x16x32_bf16(a1, Bfr[kt], acc1, 0, 0, 0);
        }

        // C/D layout: col = lane&15, row = (lane>>4)*4 + reg  [m89-verified]
        const int prow = (lane >> 4) * 4;
        const int pcol = lane & 15;
        #pragma unroll
        for (int r = 0; r < 4; ++r) {
            part[wave][prow + r][pcol]      = acc0[r];
            part[wave][16 + prow + r][pcol] = acc1[r];
        }
        __syncthreads();

        // fused update on this thread's two elements (state in registers)
        const float h0 = part[0][sb][nl0] + part[1][sb][nl0]
                       + part[2][sb][nl0] + part[3][sb][nl0];
        const float h1 = part[0][sb][nl0+1] + part[1][sb][nl0+1]
                       + part[2][sb][nl0+1] + part[3][sb][nl0+1];
        rc0 = rc0 * 0.95122945f + h0 * 0.05f;   // exp(-dt/tau_syn), dt/tau_syn
        rc1 = rc1 * 0.95122945f + h1 * 0.05f;
        rt0 = rt0 * 0.90483743f + fmaxf(ffv0 + rc0, 0.0f) * 0.1f; // exp(-dt/tau), dt/tau
        rt1 = rt1 * 0.90483743f + fmaxf(ffv1 + rc1, 0.0f) * 0.1f;
        if (t >= 90) { ac0 += rt0; ac1 += rt1; }
        // publish new rates straight to the coherence point (sc1 store,
        // fragment layout — exactly one dword per thread)
        st_coh((int*)(wbuf + fo), (int)pack2bf(rt0, rt1));

        // record: windows end at t = 100,110,...,290 (first window = 11 terms
        // /10, matching cs[100]-cs[89] in the reference)
        if (t >= 100 && (t % 10) == 0) {
            const int w = (t - 100) / 10;
            float* op = out + ((size_t)sb * 20 + w) * NN + n0 + nl0;
            op[0] = ac0 * 0.1f;
            op[1] = ac1 * 0.1f;
            ac0 = 0.0f; ac1 = 0.0f;
        }

        epoch++;
        grid_barrier(flags, epoch);  // publishes new rates; orders LDS reuse
    }
}

extern "C" void kernel_launch(void* const* d_in, const int* in_sizes, int n_in,
                              void* d_out, int out_size, void* d_ws, size_t ws_size,
                              hipStream_t stream)
{
    const float* W    = (const float*)d_in[0];   // Wab_T [4096,4096] fp32, row-major [k][n]
    const float* ff   = (const float*)d_in[1];   // [32,300,4096] fp32
    const float* rec0 = (const float*)d_in[2];   // [32,4096] fp32
    float* out = (float*)d_out;                  // [32,20,4096] fp32

    int*   flags  = (int*)d_ws;                    // 256 flags, 256B apart (64KB)
    short* ratesA = (short*)((char*)d_ws + 65536); // bf16 rates double buffer
    short* ratesB = ratesA + NB * NN;

    hipMemsetAsync(d_ws, 0, 65536, stream);        // graph-capturable memset node

    rnn_kernel<<<dim3(NBLK), dim3(256), 0, stream>>>(W, ff, rec0, out,
                                                     flags, ratesA, ratesB);
}